// Round 5
// baseline (13868.140 us; speedup 1.0000x reference)
//
#include <hip/hip_runtime.h>

#define S_   1024
#define ND   30
#define EPS_ 1e-6f

// sign of e_a * e_b in Cl(4,1): returns 1 if negative, 0 if positive.
__device__ __forceinline__ int cayley_neg(int a, int b) {
    int par = 0;
    for (int t = a >> 1; t; t >>= 1) par ^= __popc(t & b) & 1;
    par ^= ((a & b) >> 4) & 1;   // metric: generator 4 has e4*e4 = -1
    return par & 1;
}

__device__ __forceinline__ float sflip(float v, unsigned bit) {
    return __uint_as_float(__float_as_uint(v) ^ (bit << 31));
}

// 256 threads = 4 waves = 1 wave/SIMD; generous VGPR+AGPR budget.
__launch_bounds__(256, 1)
__global__ void versor_kernel(const float* __restrict__ x,
                              const float* __restrict__ W_in,
                              const float* __restrict__ b_in,
                              const float* __restrict__ w_h,
                              const float* __restrict__ w_x,
                              const float* __restrict__ W_out,
                              const float* __restrict__ b_out,
                              float* __restrict__ out) {
    const int b   = blockIdx.x;
    const int tid = threadIdx.x;          // 0..255
    const int o   = tid >> 4;             // 0..15 : channel
    const int u   = tid & 15;             // 0..15 : lane-in-group
    const int nA  = u;                    // this thread's two n-columns
    const int nB  = u + 16;

    __shared__ __align__(16) float gmi[32][36];   // G[m][ich], padded rows
    __shared__ float xt[32];
    __shared__ __align__(16) float hlds[512];
    __shared__ float red[8 * 32];

    // ---- per-thread constants (compiler AGPR-assists the overflow) ----
    float wA[32], wB[32];                 // W[(o,nA/nB)][ich]
    #pragma unroll
    for (int i = 0; i < 16; ++i) {
        wA[i]      = w_h[(o * 16 + i) * 32 + nA];
        wA[i + 16] = w_x[(o * 16 + i) * 32 + nA];
        wB[i]      = w_h[(o * 16 + i) * 32 + nB];
        wB[i + 16] = w_x[(o * 16 + i) * 32 + nB];
    }
    const int c1 = tid, c2 = tid + 256;   // this thread's two xe columns
    float win1[ND], win2[ND];
    #pragma unroll
    for (int p = 0; p < ND; ++p) {
        win1[p] = W_in[p * 512 + c1];
        win2[p] = W_in[p * 512 + c2];
    }
    const float bin1 = b_in[c1], bin2 = b_in[c2];

    const int g  = tid >> 5;              // 0..7 : out-phase j-group
    const int pl = tid & 31;              // out-phase output column
    const int pc = (pl < ND) ? pl : 0;
    float wout[64];                       // W_out[g*64+jj][pc]
    #pragma unroll
    for (int jj = 0; jj < 64; ++jj) wout[jj] = W_out[(g * 64 + jj) * ND + pc];
    const float bout_reg = (tid < ND) ? b_out[tid] : 0.0f;

    unsigned sbA = 0, sbB = 0;            // bit m: sign of s(m, nA/nB)
    for (int m = 0; m < 32; ++m) {
        sbA |= (unsigned)cayley_neg(m, nA) << m;
        sbB |= (unsigned)cayley_neg(m, nB) << m;
    }

    const int mm1 = c1 & 31, ii1 = c1 >> 5;   // xe write slots
    const int mm2 = c2 & 31, ii2 = c2 >> 5;

    float hA = 0.0f, hB = 0.0f;
    gmi[u][o]      = 0.0f;                // h-part of G starts at zero
    gmi[u + 16][o] = 0.0f;

    const float* xrow = x   + (size_t)b * S_ * ND;
    float*       orow = out + (size_t)b * S_ * ND;

    for (int s = 0; s < S_; ++s) {
        if (tid < ND) xt[tid] = xrow[s * ND + tid];
        __syncthreads();                  // B1: xt ready; prev-step LDS reuse safe

        // ---- x_emb for columns c1, c2 ----
        float xe1 = bin1, xe2 = bin2;
        #pragma unroll
        for (int p = 0; p < ND; ++p) {
            float xv = xt[p];
            xe1 = fmaf(xv, win1[p], xe1);
            xe2 = fmaf(xv, win2[p], xe2);
        }
        gmi[mm1][16 + ii1] = xe1;
        gmi[mm2][16 + ii2] = xe2;
        __syncthreads();                  // B2: G complete (h-part from prev step)

        // ---- T-phase: a0[m] = G[m,:].wA, a1[m] = G[m,:].wB (uniform b128) ----
        float a0[32], a1[32];
        #pragma unroll
        for (int m = 0; m < 32; ++m) {
            const float* gp = &gmi[m][0];
            float p0 = 0.f, p1 = 0.f, q0 = 0.f, q1 = 0.f;
            #pragma unroll
            for (int q = 0; q < 8; ++q) {
                float4 gv = *(const float4*)(gp + q * 4);   // uniform -> broadcast
                p0 = fmaf(gv.x, wA[q * 4 + 0], p0);
                p1 = fmaf(gv.y, wA[q * 4 + 1], p1);
                p0 = fmaf(gv.z, wA[q * 4 + 2], p0);
                p1 = fmaf(gv.w, wA[q * 4 + 3], p1);
                q0 = fmaf(gv.x, wB[q * 4 + 0], q0);
                q1 = fmaf(gv.y, wB[q * 4 + 1], q1);
                q0 = fmaf(gv.z, wB[q * 4 + 2], q0);
                q1 = fmaf(gv.w, wB[q * 4 + 3], q1);
            }
            a0[m] = p0 + p1;
            a1[m] = q0 + q1;
        }

        // ---- in-thread fold: c[j] = s(j,nA)a0[j] + s(j^16,nB)a1[j^16] ----
        float c[32];
        #pragma unroll
        for (int j = 0; j < 32; ++j) {
            float sa = sflip(a0[j],      (sbA >> j)        & 1u);
            float sb = sflip(a1[j ^ 16], (sbB >> (j ^ 16)) & 1u);
            c[j] = sa + sb;
        }

        // ---- 16-lane butterfly (folded): delta[u]=c[0], delta[u+16]=c[16] ----
        #pragma unroll
        for (int j = 0; j < 32; j += 2)  c[j] += __shfl_xor(c[j ^ 1], 1, 16);
        #pragma unroll
        for (int j = 0; j < 32; j += 4)  c[j] += __shfl_xor(c[j ^ 2], 2, 16);
        #pragma unroll
        for (int j = 0; j < 32; j += 8)  c[j] += __shfl_xor(c[j ^ 4], 4, 16);
        c[0]  += __shfl_xor(c[8],  8, 16);
        c[16] += __shfl_xor(c[24], 8, 16);

        // ---- residual + per-channel L2 normalize (16 lanes x 2 comps) ----
        float hcA = hA + c[0];
        float hcB = hB + c[16];
        float ss = hcA * hcA + hcB * hcB;
        #pragma unroll
        for (int mask = 1; mask < 16; mask <<= 1) ss += __shfl_xor(ss, mask, 16);
        float inv = 1.0f / (sqrtf(ss) + EPS_);
        hA = hcA * inv;
        hB = hcB * inv;

        __syncthreads();                  // B3: all T-phase G reads done
        gmi[u][o]      = hA;              // h for next step
        gmi[u + 16][o] = hB;
        hlds[o * 32 + u]      = hA;       // for out-phase
        hlds[o * 32 + u + 16] = hB;
        __syncthreads();                  // B4: hlds visible

        // ---- output: out[p] = x_t[p] + h . W_out[:,p] + b_out[p] ----
        float oacc = 0.0f;
        #pragma unroll
        for (int q = 0; q < 16; ++q) {
            float4 hv = *(const float4*)&hlds[g * 64 + q * 4];  // uniform per group
            oacc = fmaf(hv.x, wout[q * 4 + 0], oacc);
            oacc = fmaf(hv.y, wout[q * 4 + 1], oacc);
            oacc = fmaf(hv.z, wout[q * 4 + 2], oacc);
            oacc = fmaf(hv.w, wout[q * 4 + 3], oacc);
        }
        red[g * 32 + pl] = oacc;
        __syncthreads();                  // B5: red ready
        if (tid < ND) {
            float ov = xt[tid] + bout_reg;
            #pragma unroll
            for (int gg = 0; gg < 8; ++gg) ov += red[gg * 32 + tid];
            orow[s * ND + tid] = ov;
        }
        // next iteration's B1 protects xt/red/gmi/hlds reuse
    }
}

extern "C" void kernel_launch(void* const* d_in, const int* in_sizes, int n_in,
                              void* d_out, int out_size, void* d_ws, size_t ws_size,
                              hipStream_t stream) {
    const float* x     = (const float*)d_in[0];
    const float* W_in  = (const float*)d_in[1];
    const float* b_in  = (const float*)d_in[2];
    const float* w_h   = (const float*)d_in[3];
    const float* w_x   = (const float*)d_in[4];
    const float* W_out = (const float*)d_in[5];
    const float* b_out = (const float*)d_in[6];
    float* outp = (float*)d_out;

    versor_kernel<<<256, 256, 0, stream>>>(x, W_in, b_in, w_h, w_x, W_out, b_out, outp);
}

// Round 6
// 7763.148 us; speedup vs baseline: 1.7864x; 1.7864x over previous
//
#include <hip/hip_runtime.h>

#define S_   1024
#define ND   30
#define EPS_ 1e-6f

// sign of e_a * e_b in Cl(4,1): returns 1 if negative, 0 if positive.
__device__ __forceinline__ int cayley_neg(int a, int b) {
    int par = 0;
    for (int t = a >> 1; t; t >>= 1) par ^= __popc(t & b) & 1;
    par ^= ((a & b) >> 4) & 1;   // metric: generator 4 has e4*e4 = -1
    return par & 1;
}

__device__ __forceinline__ float sflip(float v, unsigned bit) {
    return __uint_as_float(__float_as_uint(v) ^ (bit << 31));
}

// 512 threads = 8 waves/CU = 2/SIMD (min for latency hiding; r5 showed 1/SIMD
// is 2x slower). (512,2) caps VGPR at 256 so 2/SIMD is guaranteed.
__launch_bounds__(512, 2)
__global__ void versor_kernel(const float* __restrict__ x,
                              const float* __restrict__ W_in,
                              const float* __restrict__ b_in,
                              const float* __restrict__ w_h,
                              const float* __restrict__ w_x,
                              const float* __restrict__ W_out,
                              const float* __restrict__ b_out,
                              float* __restrict__ out) {
    const int b   = blockIdx.x;
    const int tid = threadIdx.x;          // 0..511
    const int o   = tid >> 5;             // 0..15 : channel group
    const int l   = tid & 31;            // 0..31 : lane in group (owns h[o][l])
    const int q   = l >> 3;               // 0..3  : ich-quarter
    const int u   = l & 7;                // 0..7  : n-subgroup

    __shared__ __align__(16) float gmi[32][36];   // G[m][ich], padded rows
    __shared__ float xt[32];
    __shared__ __align__(16) float hlds[512];
    __shared__ float red[16 * 32];

    // ---- per-thread constants ----
    // w4[j][c]: float4 of W[o, ich = q*8+4c .. +3, n = u+8j]
    const float* wsrc = (q < 2) ? w_h : w_x;      // quarter 0,1 -> w_h; 2,3 -> w_x
    float4 w4[4][2];
    #pragma unroll
    for (int j = 0; j < 4; ++j) {
        const int n = u + 8 * j;
        #pragma unroll
        for (int c = 0; c < 2; ++c) {
            const int r = o * 16 + (q & 1) * 8 + 4 * c;
            float4 t;
            t.x = wsrc[(r + 0) * 32 + n];
            t.y = wsrc[(r + 1) * 32 + n];
            t.z = wsrc[(r + 2) * 32 + n];
            t.w = wsrc[(r + 3) * 32 + n];
            w4[j][c] = t;
        }
    }
    float win_reg[ND];                    // column tid of W_in
    #pragma unroll
    for (int p = 0; p < ND; ++p) win_reg[p] = W_in[p * 512 + tid];
    const float bin_reg = b_in[tid];

    const int pc = (l < ND) ? l : 0;
    float wout[32];                       // W_out[(o*32+jj)][pc]
    #pragma unroll
    for (int jj = 0; jj < 32; ++jj) wout[jj] = W_out[(o * 32 + jj) * ND + pc];
    const float bout_reg = (tid < ND) ? b_out[tid] : 0.0f;

    unsigned sb[4];                       // sb[j] bit m = sign s(m, u+8j)
    #pragma unroll
    for (int j = 0; j < 4; ++j) {
        unsigned sbj = 0;
        for (int m = 0; m < 32; ++m) sbj |= (unsigned)cayley_neg(m, u + 8 * j) << m;
        sb[j] = sbj;
    }

    float h_reg = 0.0f;
    gmi[l][o] = 0.0f;                     // h-part of G starts at zero

    const float* xrow = x   + (size_t)b * S_ * ND;
    float*       orow = out + (size_t)b * S_ * ND;

    for (int s = 0; s < S_; ++s) {
        if (tid < ND) xt[tid] = xrow[s * ND + tid];
        __syncthreads();                  // B1: xt ready; prev-step LDS reuse safe

        // ---- x_emb column tid -> G[l][16+o] ----
        float xe = bin_reg;
        #pragma unroll
        for (int p = 0; p < ND; ++p) xe = fmaf(xt[p], win_reg[p], xe);
        gmi[l][16 + o] = xe;
        __syncthreads();                  // B2: G complete (h-part from prev step)

        // ---- T-phase over this thread's ich-slice, folded into y ----
        // y[m ^ 8j] += s(m, u+8j) * (G[m, 8q..8q+8) . w4[j])
        float y[32];
        #pragma unroll
        for (int t = 0; t < 32; ++t) y[t] = 0.0f;
        #pragma unroll
        for (int m = 0; m < 32; ++m) {
            const float* gp = &gmi[m][q * 8];
            float4 g0 = *(const float4*)gp;         // 16-lane-uniform broadcast
            float4 g1 = *(const float4*)(gp + 4);
            float d0, d1, d2, d3;
            d0 = g0.x * w4[0][0].x; d1 = g0.x * w4[1][0].x;
            d2 = g0.x * w4[2][0].x; d3 = g0.x * w4[3][0].x;
            d0 = fmaf(g0.y, w4[0][0].y, d0); d1 = fmaf(g0.y, w4[1][0].y, d1);
            d2 = fmaf(g0.y, w4[2][0].y, d2); d3 = fmaf(g0.y, w4[3][0].y, d3);
            d0 = fmaf(g0.z, w4[0][0].z, d0); d1 = fmaf(g0.z, w4[1][0].z, d1);
            d2 = fmaf(g0.z, w4[2][0].z, d2); d3 = fmaf(g0.z, w4[3][0].z, d3);
            d0 = fmaf(g0.w, w4[0][0].w, d0); d1 = fmaf(g0.w, w4[1][0].w, d1);
            d2 = fmaf(g0.w, w4[2][0].w, d2); d3 = fmaf(g0.w, w4[3][0].w, d3);
            d0 = fmaf(g1.x, w4[0][1].x, d0); d1 = fmaf(g1.x, w4[1][1].x, d1);
            d2 = fmaf(g1.x, w4[2][1].x, d2); d3 = fmaf(g1.x, w4[3][1].x, d3);
            d0 = fmaf(g1.y, w4[0][1].y, d0); d1 = fmaf(g1.y, w4[1][1].y, d1);
            d2 = fmaf(g1.y, w4[2][1].y, d2); d3 = fmaf(g1.y, w4[3][1].y, d3);
            d0 = fmaf(g1.z, w4[0][1].z, d0); d1 = fmaf(g1.z, w4[1][1].z, d1);
            d2 = fmaf(g1.z, w4[2][1].z, d2); d3 = fmaf(g1.z, w4[3][1].z, d3);
            d0 = fmaf(g1.w, w4[0][1].w, d0); d1 = fmaf(g1.w, w4[1][1].w, d1);
            d2 = fmaf(g1.w, w4[2][1].w, d2); d3 = fmaf(g1.w, w4[3][1].w, d3);
            y[m]      += sflip(d0, (sb[0] >> m) & 1u);
            y[m ^ 8]  += sflip(d1, (sb[1] >> m) & 1u);
            y[m ^ 16] += sflip(d2, (sb[2] >> m) & 1u);
            y[m ^ 24] += sflip(d3, (sb[3] >> m) & 1u);
        }

        // ---- butterfly over u bits (1,2,4), then sum q-replicas (8,16) ----
        #pragma unroll
        for (int t = 0; t < 32; t += 2) y[t] += __shfl_xor(y[t ^ 1], 1, 32);
        #pragma unroll
        for (int t = 0; t < 32; t += 4) y[t] += __shfl_xor(y[t ^ 2], 2, 32);
        #pragma unroll
        for (int t = 0; t < 32; t += 8) y[t] += __shfl_xor(y[t ^ 4], 4, 32);
        #pragma unroll
        for (int r = 0; r < 32; r += 8) y[r] += __shfl_xor(y[r], 8, 32);
        #pragma unroll
        for (int r = 0; r < 32; r += 8) y[r] += __shfl_xor(y[r], 16, 32);
        // lane l = 8q+u owns delta[l] = y[8q]
        const float delta = (q == 0) ? y[0] : (q == 1) ? y[8] : (q == 2) ? y[16] : y[24];

        // ---- residual + per-channel L2 normalize ----
        float hc = h_reg + delta;
        float ss = hc * hc;
        #pragma unroll
        for (int mask = 1; mask < 32; mask <<= 1) ss += __shfl_xor(ss, mask, 32);
        h_reg = hc / (sqrtf(ss) + EPS_);

        __syncthreads();                  // B3: all T-phase G reads done (race fix)
        gmi[l][o]       = h_reg;          // h for next step
        hlds[o * 32 + l] = h_reg;         // for out-phase
        __syncthreads();                  // B4: hlds visible

        // ---- output: out[p] = x_t[p] + h . W_out[:,p] + b_out[p] ----
        float oacc = 0.0f;
        #pragma unroll
        for (int qq = 0; qq < 8; ++qq) {
            float4 hv = *(const float4*)&hlds[o * 32 + qq * 4];  // uniform per group
            oacc = fmaf(hv.x, wout[qq * 4 + 0], oacc);
            oacc = fmaf(hv.y, wout[qq * 4 + 1], oacc);
            oacc = fmaf(hv.z, wout[qq * 4 + 2], oacc);
            oacc = fmaf(hv.w, wout[qq * 4 + 3], oacc);
        }
        red[o * 32 + l] = oacc;
        __syncthreads();                  // B5: red ready
        if (tid < ND) {
            float ov = xt[tid] + bout_reg;
            #pragma unroll
            for (int gg = 0; gg < 16; ++gg) ov += red[gg * 32 + tid];
            orow[s * ND + tid] = ov;
        }
        // next iteration's B1 protects xt/red/gmi/hlds reuse
    }
}

extern "C" void kernel_launch(void* const* d_in, const int* in_sizes, int n_in,
                              void* d_out, int out_size, void* d_ws, size_t ws_size,
                              hipStream_t stream) {
    const float* x     = (const float*)d_in[0];
    const float* W_in  = (const float*)d_in[1];
    const float* b_in  = (const float*)d_in[2];
    const float* w_h   = (const float*)d_in[3];
    const float* w_x   = (const float*)d_in[4];
    const float* W_out = (const float*)d_in[5];
    const float* b_out = (const float*)d_in[6];
    float* outp = (float*)d_out;

    versor_kernel<<<256, 512, 0, stream>>>(x, W_in, b_in, w_h, w_x, W_out, b_out, outp);
}

// Round 7
// 7755.376 us; speedup vs baseline: 1.7882x; 1.0010x over previous
//
#include <hip/hip_runtime.h>

#define S_   1024
#define ND   30
#define EPS_ 1e-6f

// sign of e_a * e_b in Cl(4,1): returns 1 if negative, 0 if positive.
__device__ __forceinline__ int cayley_neg(int a, int b) {
    int par = 0;
    for (int t = a >> 1; t; t >>= 1) par ^= __popc(t & b) & 1;
    par ^= ((a & b) >> 4) & 1;   // metric: generator 4 has e4*e4 = -1
    return par & 1;
}

__device__ __forceinline__ float sflip(float v, unsigned bit) {
    return __uint_as_float(__float_as_uint(v) ^ (bit << 31));
}

// ---------- Kernel A: xg[row][m*16+ii] = b_in[c] + x[row,:].W_in[:,c], c=ii*32+m
// Uniform x addressing -> compiler scalarizes to s_load broadcasts (x immutable).
__launch_bounds__(512)
__global__ void xemb_kernel(const float* __restrict__ x,
                            const float* __restrict__ W_in,
                            const float* __restrict__ b_in,
                            float* __restrict__ xg) {
    const int t  = threadIdx.x;
    const int m  = t >> 4, ii = t & 15;
    const int c  = ii * 32 + m;
    float win[ND];
    #pragma unroll
    for (int p = 0; p < ND; ++p) win[p] = W_in[p * 512 + c];
    const float bin = b_in[c];
    const long rb0 = (long)blockIdx.x * 128;

    for (int batch = 0; batch < 8; ++batch) {
        const long rb = rb0 + batch * 16;
        float acc[16];
        #pragma unroll
        for (int r = 0; r < 16; ++r) acc[r] = bin;
        #pragma unroll
        for (int p = 0; p < ND; ++p) {
            #pragma unroll
            for (int r = 0; r < 16; ++r)
                acc[r] = fmaf(x[(rb + r) * ND + p], win[p], acc[r]);
        }
        #pragma unroll
        for (int r = 0; r < 16; ++r)
            xg[(rb + r) * 512 + t] = acc[r];
    }
}

// ---------- Kernel B: sequential RNN. h-half of G from LDS, xe-half from xg.
__launch_bounds__(512, 2)
__global__ void versor_rnn(const float* __restrict__ x,
                           const float* __restrict__ w_h,
                           const float* __restrict__ w_x,
                           const float* __restrict__ W_out,
                           const float* __restrict__ b_out,
                           const float* __restrict__ xg,
                           float* __restrict__ out) {
    const int b   = blockIdx.x;
    const int tid = threadIdx.x;          // 0..511
    const int o   = tid >> 5;             // 0..15 : channel group
    const int l   = tid & 31;             // 0..31 : lane in group (owns h[o][l])
    const int q   = l >> 3;               // 0..3  : ich-quarter
    const int u   = l & 7;                // 0..7  : n-subgroup

    __shared__ __align__(16) float gmi[32][20];   // h-half of G: [m][ich<16], padded
    __shared__ __align__(16) float hlds[512];
    __shared__ float red[16 * 32];

    // ---- per-thread constants ----
    const float* wsrc = (q < 2) ? w_h : w_x;      // quarter 0,1 -> w_h; 2,3 -> w_x
    float4 w4[4][2];
    #pragma unroll
    for (int j = 0; j < 4; ++j) {
        const int n = u + 8 * j;
        #pragma unroll
        for (int c = 0; c < 2; ++c) {
            const int r = o * 16 + (q & 1) * 8 + 4 * c;
            float4 t;
            t.x = wsrc[(r + 0) * 32 + n];
            t.y = wsrc[(r + 1) * 32 + n];
            t.z = wsrc[(r + 2) * 32 + n];
            t.w = wsrc[(r + 3) * 32 + n];
            w4[j][c] = t;
        }
    }
    const int pc = (l < ND) ? l : 0;
    float wout[32];                       // W_out[(o*32+jj)][pc]
    #pragma unroll
    for (int jj = 0; jj < 32; ++jj) wout[jj] = W_out[(o * 32 + jj) * ND + pc];
    const float bout_reg = (tid < ND) ? b_out[tid] : 0.0f;

    unsigned sb[4];                       // sb[j] bit m = sign s(m, u+8j)
    #pragma unroll
    for (int j = 0; j < 4; ++j) {
        unsigned sbj = 0;
        for (int m = 0; m < 32; ++m) sbj |= (unsigned)cayley_neg(m, u + 8 * j) << m;
        sb[j] = sbj;
    }

    float h_reg = 0.0f;
    gmi[l][o] = 0.0f;                     // h-part of G starts at zero
    __syncthreads();

    const float* xrow = x   + (size_t)b * S_ * ND;
    float*       orow = out + (size_t)b * S_ * ND;

    for (int s = 0; s < S_; ++s) {
        const size_t row = (size_t)b * S_ + s;
        const float* xgr = xg + row * 512;
        float xv = (tid < ND) ? xrow[s * ND + tid] : 0.0f;   // for residual out

        // ---- T-phase: y[m ^ 8j] += s(m,u+8j) * (G[m, 8q..8q+8) . w4[j]) ----
        // q<2: h-half from LDS; q>=2: xe-half from global xg (L1-hot, prefetched)
        float y[32];
        #pragma unroll
        for (int t = 0; t < 32; ++t) y[t] = 0.0f;
        #pragma unroll
        for (int m = 0; m < 32; ++m) {
            float4 g0, g1;
            if (q < 2) {
                const float* gp = &gmi[m][q * 8];
                g0 = *(const float4*)gp;
                g1 = *(const float4*)(gp + 4);
            } else {
                const float* gp = xgr + m * 16 + (q - 2) * 8;
                g0 = *(const float4*)gp;
                g1 = *(const float4*)(gp + 4);
            }
            float d0, d1, d2, d3;
            d0 = g0.x * w4[0][0].x; d1 = g0.x * w4[1][0].x;
            d2 = g0.x * w4[2][0].x; d3 = g0.x * w4[3][0].x;
            d0 = fmaf(g0.y, w4[0][0].y, d0); d1 = fmaf(g0.y, w4[1][0].y, d1);
            d2 = fmaf(g0.y, w4[2][0].y, d2); d3 = fmaf(g0.y, w4[3][0].y, d3);
            d0 = fmaf(g0.z, w4[0][0].z, d0); d1 = fmaf(g0.z, w4[1][0].z, d1);
            d2 = fmaf(g0.z, w4[2][0].z, d2); d3 = fmaf(g0.z, w4[3][0].z, d3);
            d0 = fmaf(g0.w, w4[0][0].w, d0); d1 = fmaf(g0.w, w4[1][0].w, d1);
            d2 = fmaf(g0.w, w4[2][0].w, d2); d3 = fmaf(g0.w, w4[3][0].w, d3);
            d0 = fmaf(g1.x, w4[0][1].x, d0); d1 = fmaf(g1.x, w4[1][1].x, d1);
            d2 = fmaf(g1.x, w4[2][1].x, d2); d3 = fmaf(g1.x, w4[3][1].x, d3);
            d0 = fmaf(g1.y, w4[0][1].y, d0); d1 = fmaf(g1.y, w4[1][1].y, d1);
            d2 = fmaf(g1.y, w4[2][1].y, d2); d3 = fmaf(g1.y, w4[3][1].y, d3);
            d0 = fmaf(g1.z, w4[0][1].z, d0); d1 = fmaf(g1.z, w4[1][1].z, d1);
            d2 = fmaf(g1.z, w4[2][1].z, d2); d3 = fmaf(g1.z, w4[3][1].z, d3);
            d0 = fmaf(g1.w, w4[0][1].w, d0); d1 = fmaf(g1.w, w4[1][1].w, d1);
            d2 = fmaf(g1.w, w4[2][1].w, d2); d3 = fmaf(g1.w, w4[3][1].w, d3);
            y[m]      += sflip(d0, (sb[0] >> m) & 1u);
            y[m ^ 8]  += sflip(d1, (sb[1] >> m) & 1u);
            y[m ^ 16] += sflip(d2, (sb[2] >> m) & 1u);
            y[m ^ 24] += sflip(d3, (sb[3] >> m) & 1u);
        }

        // ---- prefetch next xg row into L1 (hides HBM first-touch) ----
        if (s < S_ - 1) {
            float pf = xgr[512 + tid];
            asm volatile("" :: "v"(pf));
        }

        // ---- butterfly over u bits (1,2,4), then sum q-replicas (8,16) ----
        #pragma unroll
        for (int t = 0; t < 32; t += 2) y[t] += __shfl_xor(y[t ^ 1], 1, 32);
        #pragma unroll
        for (int t = 0; t < 32; t += 4) y[t] += __shfl_xor(y[t ^ 2], 2, 32);
        #pragma unroll
        for (int t = 0; t < 32; t += 8) y[t] += __shfl_xor(y[t ^ 4], 4, 32);
        #pragma unroll
        for (int r = 0; r < 32; r += 8) y[r] += __shfl_xor(y[r], 8, 32);
        #pragma unroll
        for (int r = 0; r < 32; r += 8) y[r] += __shfl_xor(y[r], 16, 32);
        const float delta = (q == 0) ? y[0] : (q == 1) ? y[8] : (q == 2) ? y[16] : y[24];

        // ---- residual + per-channel L2 normalize ----
        float hc = h_reg + delta;
        float ss = hc * hc;
        #pragma unroll
        for (int mask = 1; mask < 32; mask <<= 1) ss += __shfl_xor(ss, mask, 32);
        h_reg = hc / (sqrtf(ss) + EPS_);

        __syncthreads();                  // B3: all T-phase gmi reads done
        gmi[l][o]        = h_reg;         // h for next step
        hlds[o * 32 + l] = h_reg;         // for out-phase
        __syncthreads();                  // B4: h visible

        // ---- output: out[p] = x_t[p] + h . W_out[:,p] + b_out[p] ----
        float oacc = 0.0f;
        #pragma unroll
        for (int qq = 0; qq < 8; ++qq) {
            float4 hv = *(const float4*)&hlds[o * 32 + qq * 4];  // uniform per group
            oacc = fmaf(hv.x, wout[qq * 4 + 0], oacc);
            oacc = fmaf(hv.y, wout[qq * 4 + 1], oacc);
            oacc = fmaf(hv.z, wout[qq * 4 + 2], oacc);
            oacc = fmaf(hv.w, wout[qq * 4 + 3], oacc);
        }
        red[o * 32 + l] = oacc;
        __syncthreads();                  // B5: red ready
        if (tid < ND) {
            float ov = xv + bout_reg;
            #pragma unroll
            for (int gg = 0; gg < 16; ++gg) ov += red[gg * 32 + tid];
            orow[s * ND + tid] = ov;
        }
        // red/hlds reuse next step is protected by B4/B5 + next-step B3 ordering
    }
}

// ---------- Fallback (ws too small): round-6 kernel, known-good ----------
__launch_bounds__(512, 2)
__global__ void versor_fallback(const float* __restrict__ x,
                                const float* __restrict__ W_in,
                                const float* __restrict__ b_in,
                                const float* __restrict__ w_h,
                                const float* __restrict__ w_x,
                                const float* __restrict__ W_out,
                                const float* __restrict__ b_out,
                                float* __restrict__ out) {
    const int b   = blockIdx.x;
    const int tid = threadIdx.x;
    const int o   = tid >> 5;
    const int l   = tid & 31;
    const int q   = l >> 3;
    const int u   = l & 7;

    __shared__ __align__(16) float gmi[32][36];
    __shared__ float xt[32];
    __shared__ __align__(16) float hlds[512];
    __shared__ float red[16 * 32];

    const float* wsrc = (q < 2) ? w_h : w_x;
    float4 w4[4][2];
    #pragma unroll
    for (int j = 0; j < 4; ++j) {
        const int n = u + 8 * j;
        #pragma unroll
        for (int c = 0; c < 2; ++c) {
            const int r = o * 16 + (q & 1) * 8 + 4 * c;
            float4 t;
            t.x = wsrc[(r + 0) * 32 + n];
            t.y = wsrc[(r + 1) * 32 + n];
            t.z = wsrc[(r + 2) * 32 + n];
            t.w = wsrc[(r + 3) * 32 + n];
            w4[j][c] = t;
        }
    }
    float win_reg[ND];
    #pragma unroll
    for (int p = 0; p < ND; ++p) win_reg[p] = W_in[p * 512 + tid];
    const float bin_reg = b_in[tid];
    const int pc = (l < ND) ? l : 0;
    float wout[32];
    #pragma unroll
    for (int jj = 0; jj < 32; ++jj) wout[jj] = W_out[(o * 32 + jj) * ND + pc];
    const float bout_reg = (tid < ND) ? b_out[tid] : 0.0f;

    unsigned sb[4];
    #pragma unroll
    for (int j = 0; j < 4; ++j) {
        unsigned sbj = 0;
        for (int m = 0; m < 32; ++m) sbj |= (unsigned)cayley_neg(m, u + 8 * j) << m;
        sb[j] = sbj;
    }

    float h_reg = 0.0f;
    gmi[l][o] = 0.0f;

    const float* xrow = x   + (size_t)b * S_ * ND;
    float*       orow = out + (size_t)b * S_ * ND;

    for (int s = 0; s < S_; ++s) {
        if (tid < ND) xt[tid] = xrow[s * ND + tid];
        __syncthreads();
        float xe = bin_reg;
        #pragma unroll
        for (int p = 0; p < ND; ++p) xe = fmaf(xt[p], win_reg[p], xe);
        gmi[l][16 + o] = xe;
        __syncthreads();
        float y[32];
        #pragma unroll
        for (int t = 0; t < 32; ++t) y[t] = 0.0f;
        #pragma unroll
        for (int m = 0; m < 32; ++m) {
            const float* gp = &gmi[m][q * 8];
            float4 g0 = *(const float4*)gp;
            float4 g1 = *(const float4*)(gp + 4);
            float d0, d1, d2, d3;
            d0 = g0.x * w4[0][0].x; d1 = g0.x * w4[1][0].x;
            d2 = g0.x * w4[2][0].x; d3 = g0.x * w4[3][0].x;
            d0 = fmaf(g0.y, w4[0][0].y, d0); d1 = fmaf(g0.y, w4[1][0].y, d1);
            d2 = fmaf(g0.y, w4[2][0].y, d2); d3 = fmaf(g0.y, w4[3][0].y, d3);
            d0 = fmaf(g0.z, w4[0][0].z, d0); d1 = fmaf(g0.z, w4[1][0].z, d1);
            d2 = fmaf(g0.z, w4[2][0].z, d2); d3 = fmaf(g0.z, w4[3][0].z, d3);
            d0 = fmaf(g0.w, w4[0][0].w, d0); d1 = fmaf(g0.w, w4[1][0].w, d1);
            d2 = fmaf(g0.w, w4[2][0].w, d2); d3 = fmaf(g0.w, w4[3][0].w, d3);
            d0 = fmaf(g1.x, w4[0][1].x, d0); d1 = fmaf(g1.x, w4[1][1].x, d1);
            d2 = fmaf(g1.x, w4[2][1].x, d2); d3 = fmaf(g1.x, w4[3][1].x, d3);
            d0 = fmaf(g1.y, w4[0][1].y, d0); d1 = fmaf(g1.y, w4[1][1].y, d1);
            d2 = fmaf(g1.y, w4[2][1].y, d2); d3 = fmaf(g1.y, w4[3][1].y, d3);
            d0 = fmaf(g1.z, w4[0][1].z, d0); d1 = fmaf(g1.z, w4[1][1].z, d1);
            d2 = fmaf(g1.z, w4[2][1].z, d2); d3 = fmaf(g1.z, w4[3][1].z, d3);
            d0 = fmaf(g1.w, w4[0][1].w, d0); d1 = fmaf(g1.w, w4[1][1].w, d1);
            d2 = fmaf(g1.w, w4[2][1].w, d2); d3 = fmaf(g1.w, w4[3][1].w, d3);
            y[m]      += sflip(d0, (sb[0] >> m) & 1u);
            y[m ^ 8]  += sflip(d1, (sb[1] >> m) & 1u);
            y[m ^ 16] += sflip(d2, (sb[2] >> m) & 1u);
            y[m ^ 24] += sflip(d3, (sb[3] >> m) & 1u);
        }
        #pragma unroll
        for (int t = 0; t < 32; t += 2) y[t] += __shfl_xor(y[t ^ 1], 1, 32);
        #pragma unroll
        for (int t = 0; t < 32; t += 4) y[t] += __shfl_xor(y[t ^ 2], 2, 32);
        #pragma unroll
        for (int t = 0; t < 32; t += 8) y[t] += __shfl_xor(y[t ^ 4], 4, 32);
        #pragma unroll
        for (int r = 0; r < 32; r += 8) y[r] += __shfl_xor(y[r], 8, 32);
        #pragma unroll
        for (int r = 0; r < 32; r += 8) y[r] += __shfl_xor(y[r], 16, 32);
        const float delta = (q == 0) ? y[0] : (q == 1) ? y[8] : (q == 2) ? y[16] : y[24];
        float hc = h_reg + delta;
        float ss = hc * hc;
        #pragma unroll
        for (int mask = 1; mask < 32; mask <<= 1) ss += __shfl_xor(ss, mask, 32);
        h_reg = hc / (sqrtf(ss) + EPS_);
        __syncthreads();
        gmi[l][o]        = h_reg;
        hlds[o * 32 + l] = h_reg;
        __syncthreads();
        float oacc = 0.0f;
        #pragma unroll
        for (int qq = 0; qq < 8; ++qq) {
            float4 hv = *(const float4*)&hlds[o * 32 + qq * 4];
            oacc = fmaf(hv.x, wout[qq * 4 + 0], oacc);
            oacc = fmaf(hv.y, wout[qq * 4 + 1], oacc);
            oacc = fmaf(hv.z, wout[qq * 4 + 2], oacc);
            oacc = fmaf(hv.w, wout[qq * 4 + 3], oacc);
        }
        red[o * 32 + l] = oacc;
        __syncthreads();
        if (tid < ND) {
            float ov = xt[tid] + bout_reg;
            #pragma unroll
            for (int gg = 0; gg < 16; ++gg) ov += red[gg * 32 + tid];
            orow[s * ND + tid] = ov;
        }
    }
}

extern "C" void kernel_launch(void* const* d_in, const int* in_sizes, int n_in,
                              void* d_out, int out_size, void* d_ws, size_t ws_size,
                              hipStream_t stream) {
    const float* x     = (const float*)d_in[0];
    const float* W_in  = (const float*)d_in[1];
    const float* b_in  = (const float*)d_in[2];
    const float* w_h   = (const float*)d_in[3];
    const float* w_x   = (const float*)d_in[4];
    const float* W_out = (const float*)d_in[5];
    const float* b_out = (const float*)d_in[6];
    float* outp = (float*)d_out;

    const size_t xg_bytes = (size_t)256 * 1024 * 512 * 4;   // 512 MB
    if (ws_size >= xg_bytes) {
        float* xg = (float*)d_ws;
        xemb_kernel<<<2048, 512, 0, stream>>>(x, W_in, b_in, xg);
        versor_rnn<<<256, 512, 0, stream>>>(x, w_h, w_x, W_out, b_out, xg, outp);
    } else {
        versor_fallback<<<256, 512, 0, stream>>>(x, W_in, b_in, w_h, w_x,
                                                 W_out, b_out, outp);
    }
}

// Round 8
// 6564.868 us; speedup vs baseline: 2.1125x; 1.1813x over previous
//
#include <hip/hip_runtime.h>

#define S_   1024
#define ND   30
#define EPS_ 1e-6f

// sign of e_a * e_b in Cl(4,1): returns 1 if negative, 0 if positive.
__device__ __forceinline__ int cayley_neg(int a, int b) {
    int par = 0;
    for (int t = a >> 1; t; t >>= 1) par ^= __popc(t & b) & 1;
    par ^= ((a & b) >> 4) & 1;   // metric: generator 4 has e4*e4 = -1
    return par & 1;
}

__device__ __forceinline__ float sflip(float v, unsigned bit) {
    return __uint_as_float(__float_as_uint(v) ^ (bit << 31));
}

// lgkmcnt-only barrier: does NOT drain vmcnt, so global stores/loads float
// across steps (a compiler __syncthreads() waits vmcnt(0) -> store-ack stall).
#define BAR() asm volatile("s_waitcnt lgkmcnt(0)\n\ts_barrier" ::: "memory")

__launch_bounds__(512, 1)
__global__ void versor_kernel(const float* __restrict__ x,
                              const float* __restrict__ W_in,
                              const float* __restrict__ b_in,
                              const float* __restrict__ w_h,
                              const float* __restrict__ w_x,
                              const float* __restrict__ W_out,
                              const float* __restrict__ b_out,
                              float* __restrict__ out) {
    const int b    = blockIdx.x;
    const int tid  = threadIdx.x;
    const int o    = tid >> 5;   // 0..15  (channel)
    const int l    = tid & 31;   // 0..31  (n in T-phase, k after butterfly)

    // Everything double-buffered on step parity: the ONLY intra-step
    // visibility edge is write(buf) ... BAR ... read(buf); all reuse hazards
    // are parity-separated (>= one barrier apart).
    __shared__ __align__(16) float gmi[2][32][36];   // G[m][ich] (h | xe)
    __shared__ __align__(16) float hlds[2][512];     // h, out-phase layout
    __shared__ float red[2][512];                    // out-phase partials

    // ---- per-thread constant registers (R1-identical) ----
    float w_reg[32];                     // W[(o,l)][ich]: w_h then w_x
    #pragma unroll
    for (int ich = 0; ich < 16; ++ich) {
        w_reg[ich]      = w_h[(o * 16 + ich) * 32 + l];
        w_reg[ich + 16] = w_x[(o * 16 + ich) * 32 + l];
    }
    float win_reg[ND];                   // column tid of W_in
    #pragma unroll
    for (int p = 0; p < ND; ++p) win_reg[p] = W_in[p * 512 + tid];
    const float bin_reg = b_in[tid];

    const int pc = (l < ND) ? l : 0;
    float wout[32];                      // W_out[(o*32+jj)][pc]
    #pragma unroll
    for (int jj = 0; jj < 32; ++jj) wout[jj] = W_out[(o * 32 + jj) * ND + pc];
    const float bout_reg = (tid < ND) ? b_out[tid] : 0.0f;

    unsigned sbits = 0;                  // bit m: sign of s(m, n=l)
    for (int m = 0; m < 32; ++m) sbits |= (unsigned)cayley_neg(m, l) << m;

    float h_reg = 0.0f;
    gmi[0][l][o] = 0.0f;                 // h_0 = 0 in buffer 0
    float xv_prev = 0.0f;

    const float* xrow = x   + (size_t)b * S_ * ND;
    float*       orow = out + (size_t)b * S_ * ND;

    // Step s (0..S_-1) computes h_{s+1}; iteration s also FINISHES out[s-1].
    // Extra iteration s==S_ finishes out[S_-1].
    for (int s = 0; s <= S_; ++s) {
        const int p = s & 1;

        // ---- stage 1: x_emb via wave-uniform loads of immutable x ----
        float xv_cur = 0.0f;
        if (s < S_) {
            const float* xp = xrow + s * ND;
            xv_cur = (tid < ND) ? xp[tid] : 0.0f;       // residual (used at s+1)
            float xe = bin_reg;
            #pragma unroll
            for (int q = 0; q < ND; ++q) xe = fmaf(xp[q], win_reg[q], xe);
            gmi[p][l][16 + o] = xe;                     // xe_s -> buf p
        }

        // ---- stage 2: out[s-1] partials from h_s (hlds buf p) ----
        if (s > 0) {
            const float* hp = &hlds[p][o * 32];
            float oacc = 0.0f;
            #pragma unroll
            for (int qq = 0; qq < 8; ++qq) {
                float4 hv = *(const float4*)(hp + qq * 4);   // uniform broadcast
                oacc = fmaf(hv.x, wout[qq * 4 + 0], oacc);
                oacc = fmaf(hv.y, wout[qq * 4 + 1], oacc);
                oacc = fmaf(hv.z, wout[qq * 4 + 2], oacc);
                oacc = fmaf(hv.w, wout[qq * 4 + 3], oacc);
            }
            red[p][o * 32 + l] = oacc;
        }

        BAR();   // the ONE barrier: G_s (h_s from s-1, xe_s), red visible

        // ---- stage 3: finish out[s-1] (global store, never drained) ----
        if (s > 0 && tid < ND) {
            float ov = xv_prev + bout_reg;
            #pragma unroll
            for (int jg = 0; jg < 16; ++jg) ov += red[p][jg * 32 + tid];
            orow[(size_t)(s - 1) * ND + tid] = ov;
        }

        if (s < S_) {
            // ---- stage 4: T-phase (R1-exact): a[m] = s(m,l) * G[m,:].w_reg ----
            float a[32];
            #pragma unroll
            for (int m = 0; m < 32; ++m) {
                const float* gp = &gmi[p][m][0];
                float t0 = 0.f, t1 = 0.f, t2 = 0.f, t3 = 0.f;
                #pragma unroll
                for (int q = 0; q < 8; ++q) {
                    float4 gv = *(const float4*)(gp + q * 4);   // uniform -> bcast
                    t0 += gv.x * w_reg[q * 4 + 0];
                    t1 += gv.y * w_reg[q * 4 + 1];
                    t2 += gv.z * w_reg[q * 4 + 2];
                    t3 += gv.w * w_reg[q * 4 + 3];
                }
                float t = (t0 + t1) + (t2 + t3);
                a[m] = sflip(t, (sbits >> m) & 1u);
            }

            // ---- stage 5: butterfly (R1-exact): delta[o,k] lands at lane k ----
            #pragma unroll
            for (int m = 0; m < 32; m += 2)  a[m] += __shfl_xor(a[m ^ 1], 1, 32);
            #pragma unroll
            for (int m = 0; m < 32; m += 4)  a[m] += __shfl_xor(a[m ^ 2], 2, 32);
            #pragma unroll
            for (int m = 0; m < 32; m += 8)  a[m] += __shfl_xor(a[m ^ 4], 4, 32);
            #pragma unroll
            for (int m = 0; m < 32; m += 16) a[m] += __shfl_xor(a[m ^ 8], 8, 32);
            a[0] += __shfl_xor(a[16], 16, 32);

            // ---- stage 6: residual + per-channel L2 normalize (R1-exact) ----
            float hc = h_reg + a[0];
            float ss = hc * hc;
            #pragma unroll
            for (int mask = 1; mask < 32; mask <<= 1) ss += __shfl_xor(ss, mask, 32);
            h_reg = hc / (sqrtf(ss) + EPS_);

            // ---- stage 7: h_{s+1} -> OTHER buffer (no barrier needed: WAR is
            // parity-separated; visibility carried by next step's BAR) ----
            gmi[p ^ 1][l][o]        = h_reg;
            hlds[p ^ 1][o * 32 + l] = h_reg;
        }

        xv_prev = xv_cur;
    }
}

extern "C" void kernel_launch(void* const* d_in, const int* in_sizes, int n_in,
                              void* d_out, int out_size, void* d_ws, size_t ws_size,
                              hipStream_t stream) {
    const float* x     = (const float*)d_in[0];
    const float* W_in  = (const float*)d_in[1];
    const float* b_in  = (const float*)d_in[2];
    const float* w_h   = (const float*)d_in[3];
    const float* w_x   = (const float*)d_in[4];
    const float* W_out = (const float*)d_in[5];
    const float* b_out = (const float*)d_in[6];
    float* outp = (float*)d_out;

    versor_kernel<<<256, 512, 0, stream>>>(x, W_in, b_in, w_h, w_x, W_out, b_out, outp);
}

// Round 9
// 2200.869 us; speedup vs baseline: 6.3012x; 2.9829x over previous
//
#include <hip/hip_runtime.h>

#define S_   1024
#define ND   30
#define EPS_ 1e-6f

typedef __attribute__((ext_vector_type(8))) short bf16x8;
typedef __attribute__((ext_vector_type(4))) float f32x4;

// sign of e_a * e_b in Cl(4,1): returns 1 if negative, 0 if positive.
__device__ __forceinline__ int cayley_neg(int a, int b) {
    int par = 0;
    for (int t = a >> 1; t; t >>= 1) par ^= __popc(t & b) & 1;
    par ^= ((a & b) >> 4) & 1;   // metric: generator 4 has e4*e4 = -1
    return par & 1;
}

__device__ __forceinline__ float sflip(float v, unsigned bit) {
    return __uint_as_float(__float_as_uint(v) ^ (bit << 31));
}

// exact fp32 -> bf16_hi + bf16_lo split (truncation; v - hi is exact)
__device__ __forceinline__ void split2(float v, ushort& hi, ushort& lo) {
    unsigned bv = __float_as_uint(v);
    hi = (ushort)(bv >> 16);
    float hv = __uint_as_float(bv & 0xffff0000u);
    lo = (ushort)(__float_as_uint(v - hv) >> 16);
}

// lgkmcnt-only barrier (never drains vmcnt -> global stores float across steps)
#define BAR() asm volatile("s_waitcnt lgkmcnt(0)\n\ts_barrier" ::: "memory")

__launch_bounds__(512, 2)
__global__ void versor_kernel(const float* __restrict__ x,
                              const float* __restrict__ W_in,
                              const float* __restrict__ b_in,
                              const float* __restrict__ w_h,
                              const float* __restrict__ w_x,
                              const float* __restrict__ W_out,
                              const float* __restrict__ b_out,
                              float* __restrict__ out) {
    const int b   = blockIdx.x;
    const int tid = threadIdx.x;
    const int w   = tid >> 6;        // wave 0..7 -> output channels {2w, 2w+1}
    const int ln  = tid & 63;        // lane in wave
    const int g   = ln >> 4;         // k-chunk (A/B frag) / m_mid (C frag) / sel
    const int cl  = ln & 15;         // A row-in-tile, B/C col-in-tile
    const int op  = ln >> 5;         // o' in {0,1}
    const int oo  = 2 * w + op;      // this thread's h channel
    const int kk  = ln & 31;         // this thread's h component
    const int oc  = tid >> 5;        // xe/out-phase channel (col = tid mapping)
    const int lc  = tid & 31;

    // G (=[h | xe]) in MFMA A-fragment layout, bf16 hi/lo, double-buffered:
    // elem = mt*512 + (ich>>3)*128 + (m&15)*8 + (ich&7)
    __shared__ ushort ghi[2][1024];
    __shared__ ushort glo[2][1024];
    __shared__ float  red[2][512];

    // ---- B fragments (W, step-constant): lane holds B[k=8g+j][nt*16+cl] ----
    bf16x8 bh[2][2], bl[2][2];       // [o'][nt]
    #pragma unroll
    for (int opi = 0; opi < 2; ++opi) {
        #pragma unroll
        for (int nt = 0; nt < 2; ++nt) {
            const int o = 2 * w + opi;
            const int n = nt * 16 + cl;
            #pragma unroll
            for (int j = 0; j < 8; ++j) {
                const int k = g * 8 + j;
                float wv = (k < 16) ? w_h[(o * 16 + k) * 32 + n]
                                    : w_x[(o * 16 + (k - 16)) * 32 + n];
                ushort h_, l_; split2(wv, h_, l_);
                bh[opi][nt][j] = (short)h_;
                bl[opi][nt][j] = (short)l_;
            }
        }
    }

    float win_reg[ND];               // column tid of W_in
    #pragma unroll
    for (int p = 0; p < ND; ++p) win_reg[p] = W_in[p * 512 + tid];
    const float bin_reg = b_in[tid];

    const int pc = (lc < ND) ? lc : 0;
    float wout[32];                  // W_out[(oc*32+jj)][pc]
    #pragma unroll
    for (int jj = 0; jj < 32; ++jj) wout[jj] = W_out[(oc * 32 + jj) * ND + pc];
    const float bout_reg = (tid < ND) ? b_out[tid] : 0.0f;

    // sign mask: bit (mt*8 + nt*4 + r) = s(m,n) for m=mt*16+g*4+r, n=nt*16+cl
    unsigned smask = 0;
    for (int mt = 0; mt < 2; ++mt)
        for (int nt = 0; nt < 2; ++nt)
            for (int r = 0; r < 4; ++r) {
                int m = mt * 16 + g * 4 + r;
                int n = nt * 16 + cl;
                smask |= (unsigned)cayley_neg(m, n) << (mt * 8 + nt * 4 + r);
            }

    // fixed LDS element offsets
    const int eh = (kk >> 4) * 512 + (oo >> 3) * 128 + (kk & 15) * 8 + (oo & 7);
    const int ex = (lc >> 4) * 512 + (2 + (oc >> 3)) * 128 + (lc & 15) * 8 + (oc & 7);
    const int ea = g * 128 + cl * 8;     // A-frag read base (+512 for mt=1)

    ghi[0][eh] = 0; glo[0][eh] = 0;      // h_0 = 0 (parity-0 h slots)

    float h_reg = 0.0f, xv_prev = 0.0f;
    const float* xrow = x   + (size_t)b * S_ * ND;
    float*       orow = out + (size_t)b * S_ * ND;
    const f32x4 z4 = {0.f, 0.f, 0.f, 0.f};

    // iter s computes h_{s+1} and finishes out[s-1]; iter S_ finishes out[S_-1]
    for (int s = 0; s <= S_; ++s) {
        const int p = s & 1;

        // ---- stage 1: xe (uniform x loads), split to bf16 hi/lo -> G[p] ----
        float xv_cur = 0.0f;
        if (s < S_) {
            const float* xp = xrow + s * ND;
            xv_cur = (tid < ND) ? xp[tid] : 0.0f;
            float xe = bin_reg;
            #pragma unroll
            for (int q = 0; q < ND; ++q) xe = fmaf(xp[q], win_reg[q], xe);
            ushort xh, xl; split2(xe, xh, xl);
            ghi[p][ex] = xh; glo[p][ex] = xl;
        }

        // ---- stage 2: out[s-1] partials from h_reg via half-wave shuffles ----
        // (register-sourced: no LDS read -> no cross-parity race)
        if (s > 0) {
            float oacc = 0.0f;
            #pragma unroll
            for (int jj = 0; jj < 32; ++jj)
                oacc = fmaf(__shfl(h_reg, jj, 32), wout[jj], oacc);
            red[p][oc * 32 + lc] = oacc;
        }

        BAR();   // the ONE barrier: G[p] (h from s-1 tail, xe), red[p] visible

        // ---- stage 3: finish out[s-1] (global store, never drained) ----
        if (s > 0 && tid < ND) {
            float ov = xv_prev + bout_reg;
            #pragma unroll
            for (int jg = 0; jg < 16; ++jg) ov += red[p][jg * 32 + tid];
            orow[(size_t)(s - 1) * ND + tid] = ov;
        }

        if (s < S_) {
            // ---- stage 4: A-fragments (per-lane distinct 16B) + 32 MFMA ----
            bf16x8 ah0 = *(const bf16x8*)&ghi[p][ea];
            bf16x8 ah1 = *(const bf16x8*)&ghi[p][ea + 512];
            bf16x8 al0 = *(const bf16x8*)&glo[p][ea];
            bf16x8 al1 = *(const bf16x8*)&glo[p][ea + 512];

            f32x4 acc[2][2][2];      // [o'][mt][nt]
            #pragma unroll
            for (int opi = 0; opi < 2; ++opi) {
                #pragma unroll
                for (int nt = 0; nt < 2; ++nt) {
                    f32x4 t = __builtin_amdgcn_mfma_f32_16x16x32_bf16(al0, bl[opi][nt], z4, 0, 0, 0);
                    t = __builtin_amdgcn_mfma_f32_16x16x32_bf16(ah0, bl[opi][nt], t, 0, 0, 0);
                    t = __builtin_amdgcn_mfma_f32_16x16x32_bf16(al0, bh[opi][nt], t, 0, 0, 0);
                    acc[opi][0][nt] = __builtin_amdgcn_mfma_f32_16x16x32_bf16(ah0, bh[opi][nt], t, 0, 0, 0);
                    f32x4 u = __builtin_amdgcn_mfma_f32_16x16x32_bf16(al1, bl[opi][nt], z4, 0, 0, 0);
                    u = __builtin_amdgcn_mfma_f32_16x16x32_bf16(ah1, bl[opi][nt], u, 0, 0, 0);
                    u = __builtin_amdgcn_mfma_f32_16x16x32_bf16(al1, bh[opi][nt], u, 0, 0, 0);
                    acc[opi][1][nt] = __builtin_amdgcn_mfma_f32_16x16x32_bf16(ah1, bh[opi][nt], u, 0, 0, 0);
                }
            }

            // ---- stage 5: sign + XOR-fold. T[m][n] at (reg r, lane): m =
            // mt*16 + g*4 + r, n = nt*16 + cl. Fold n-bits; k = m^n.
            // b4 (mu=16, registers): keep mt=0, kt := nt
            float Y[2][2][4];
            #pragma unroll
            for (int opi = 0; opi < 2; ++opi)
                #pragma unroll
                for (int nt = 0; nt < 2; ++nt)
                    #pragma unroll
                    for (int r = 0; r < 4; ++r) {
                        float v0 = sflip(acc[opi][0][nt][r],     (smask >> (nt * 4 + r)) & 1u);
                        float v1 = sflip(acc[opi][1][nt ^ 1][r], (smask >> (8 + (nt ^ 1) * 4 + r)) & 1u);
                        Y[opi][nt][r] = v0 + v1;
                    }
            // b0 (mu=1): lane^1, reg r^1 ; keep r in {0,2}
            // b1 (mu=2): lane^2, reg r^2 ; keep r=0
            // b2 (mu=4): m-bit2=lane4, n-bit2=lane2 -> mask 20
            // b3 (mu=8): m-bit3=lane5, n-bit3=lane3 -> mask 40
            float Z[2][2];
            #pragma unroll
            for (int opi = 0; opi < 2; ++opi) {
                #pragma unroll
                for (int kt = 0; kt < 2; ++kt) {
                    float ya0 = Y[opi][kt][0] + __shfl_xor(Y[opi][kt][1], 1, 64);
                    float ya2 = Y[opi][kt][2] + __shfl_xor(Y[opi][kt][3], 1, 64);
                    float z = ya0 + __shfl_xor(ya2, 2, 64);
                    z += __shfl_xor(z, 20, 64);
                    z += __shfl_xor(z, 40, 64);
                    Z[opi][kt] = z;
                }
            }
            // redistribute: lanes 0..15 (m_mid=0, r=0) hold delta[o'][kt*16+lane]
            float d0 = __shfl(Z[0][0], cl, 64);
            float d1 = __shfl(Z[0][1], cl, 64);
            float d2 = __shfl(Z[1][0], cl, 64);
            float d3 = __shfl(Z[1][1], cl, 64);
            const float delta = (g == 0) ? d0 : (g == 1) ? d1 : (g == 2) ? d2 : d3;

            // ---- stage 6: residual + per-channel L2 normalize ----
            float hc = h_reg + delta;
            float ss = hc * hc;
            #pragma unroll
            for (int mask = 1; mask < 32; mask <<= 1) ss += __shfl_xor(ss, mask, 32);
            h_reg = hc / (sqrtf(ss) + EPS_);

            // ---- stage 7: h_{s+1} -> parity p^1 (visible after next BAR) ----
            ushort hh, hl; split2(h_reg, hh, hl);
            ghi[p ^ 1][eh] = hh; glo[p ^ 1][eh] = hl;
        }

        xv_prev = xv_cur;
    }
}

extern "C" void kernel_launch(void* const* d_in, const int* in_sizes, int n_in,
                              void* d_out, int out_size, void* d_ws, size_t ws_size,
                              hipStream_t stream) {
    const float* x     = (const float*)d_in[0];
    const float* W_in  = (const float*)d_in[1];
    const float* b_in  = (const float*)d_in[2];
    const float* w_h   = (const float*)d_in[3];
    const float* w_x   = (const float*)d_in[4];
    const float* W_out = (const float*)d_in[5];
    const float* b_out = (const float*)d_in[6];
    float* outp = (float*)d_out;

    versor_kernel<<<256, 512, 0, stream>>>(x, W_in, b_in, w_h, w_x, W_out, b_out, outp);
}

// Round 11
// 1495.750 us; speedup vs baseline: 9.2717x; 1.4714x over previous
//
#include <hip/hip_runtime.h>

#define S_   1024
#define ND   30
#define EPS_ 1e-6f

typedef __attribute__((ext_vector_type(8))) short bf16x8;
typedef __attribute__((ext_vector_type(4))) float f32x4;

// sign of e_a * e_b in Cl(4,1): returns 1 if negative, 0 if positive.
__device__ __forceinline__ int cayley_neg(int a, int b) {
    int par = 0;
    for (int t = a >> 1; t; t >>= 1) par ^= __popc(t & b) & 1;
    par ^= ((a & b) >> 4) & 1;   // metric: generator 4 has e4*e4 = -1
    return par & 1;
}

__device__ __forceinline__ float sflip(float v, unsigned bit) {
    return __uint_as_float(__float_as_uint(v) ^ (bit << 31));
}

// exact fp32 -> bf16_hi + bf16_lo split (truncation; v - hi is exact)
__device__ __forceinline__ void split2(float v, ushort& hi, ushort& lo) {
    unsigned bv = __float_as_uint(v);
    hi = (ushort)(bv >> 16);
    float hv = __uint_as_float(bv & 0xffff0000u);
    lo = (ushort)(__float_as_uint(v - hv) >> 16);
}

// cross-lane xor-1 / xor-2 on the VALU (DPP quad_perm) instead of the DS pipe
__device__ __forceinline__ float dpp_xor1(float v) {
    return __int_as_float(__builtin_amdgcn_update_dpp(
        0, __float_as_int(v), 0xB1 /*quad_perm 1,0,3,2*/, 0xF, 0xF, true));
}
__device__ __forceinline__ float dpp_xor2(float v) {
    return __int_as_float(__builtin_amdgcn_update_dpp(
        0, __float_as_int(v), 0x4E /*quad_perm 2,3,0,1*/, 0xF, 0xF, true));
}

// lgkmcnt-only barrier (never drains vmcnt -> global stores/loads float freely)
#define BAR() asm volatile("s_waitcnt lgkmcnt(0)\n\ts_barrier" ::: "memory")

__launch_bounds__(512, 2)
__global__ void versor_kernel(const float* __restrict__ x,
                              const float* __restrict__ W_in,
                              const float* __restrict__ b_in,
                              const float* __restrict__ w_h,
                              const float* __restrict__ w_x,
                              const float* __restrict__ W_out,
                              const float* __restrict__ b_out,
                              float* __restrict__ out) {
    const int b   = blockIdx.x;
    const int tid = threadIdx.x;
    const int w   = tid >> 6;        // wave 0..7 -> output channels {2w, 2w+1}
    const int ln  = tid & 63;        // lane in wave
    const int g   = ln >> 4;         // k-chunk (A/B frag) / m_mid (C frag) / sel
    const int cl  = ln & 15;         // A row-in-tile, B/C col-in-tile
    const int op  = ln >> 5;         // o' in {0,1}
    const int oo  = 2 * w + op;      // this thread's h channel
    const int kk  = ln & 31;         // this thread's h component
    const int oc  = tid >> 5;        // out-phase channel group (== oo)
    const int lc  = tid & 31;        // out-phase column lane   (== kk)

    // G (=[h | xe]) in MFMA A-fragment layout, bf16 hi/lo, double-buffered:
    // elem = mt*512 + (ich>>3)*128 + (m&15)*8 + (ich&7)
    __shared__ ushort ghi[2][1024];
    __shared__ ushort glo[2][1024];
    __shared__ __align__(16) float hlds[2][512];   // h_{s+1} at parity (s+1)&1
    __shared__ float red[2][512];

    // ---- B fragments (W, step-constant): lane holds B[k=8g+j][nt*16+cl] ----
    bf16x8 bh[2][2], bl[2][2];       // [o'][nt]
    #pragma unroll
    for (int opi = 0; opi < 2; ++opi) {
        #pragma unroll
        for (int nt = 0; nt < 2; ++nt) {
            const int o = 2 * w + opi;
            const int n = nt * 16 + cl;
            #pragma unroll
            for (int j = 0; j < 8; ++j) {
                const int k = g * 8 + j;
                float wv = (k < 16) ? w_h[(o * 16 + k) * 32 + n]
                                    : w_x[(o * 16 + (k - 16)) * 32 + n];
                ushort h_, l_; split2(wv, h_, l_);
                bh[opi][nt][j] = (short)h_;
                bl[opi][nt][j] = (short)l_;
            }
        }
    }

    float win_reg[ND];               // column tid of W_in
    #pragma unroll
    for (int p = 0; p < ND; ++p) win_reg[p] = W_in[p * 512 + tid];
    const float bin_reg = b_in[tid];

    const int pc = (lc < ND) ? lc : 0;
    float wout[32];                  // W_out[(oc*32+jj)][pc]
    #pragma unroll
    for (int jj = 0; jj < 32; ++jj) wout[jj] = W_out[(oc * 32 + jj) * ND + pc];
    const float bout_reg = (tid < ND) ? b_out[tid] : 0.0f;

    // sign mask: bit (mt*8 + nt*4 + r) = s(m,n) for m=mt*16+g*4+r, n=nt*16+cl
    unsigned smask = 0;
    for (int mt = 0; mt < 2; ++mt)
        for (int nt = 0; nt < 2; ++nt)
            for (int r = 0; r < 4; ++r) {
                int m = mt * 16 + g * 4 + r;
                int n = nt * 16 + cl;
                smask |= (unsigned)cayley_neg(m, n) << (mt * 8 + nt * 4 + r);
            }

    // fixed LDS element offsets
    const int eh = (kk >> 4) * 512 + (oo >> 3) * 128 + (kk & 15) * 8 + (oo & 7);
    const int ex = (lc >> 4) * 512 + (2 + (oc >> 3)) * 128 + (lc & 15) * 8 + (oc & 7);
    const int ea = g * 128 + cl * 8;     // A-frag read base (+512 for mt=1)

    ghi[0][eh] = 0; glo[0][eh] = 0;      // h_0 = 0 (parity-0 h slots)

    float h_reg = 0.0f, xv_prev = 0.0f;
    const float* xrow = x   + (size_t)b * S_ * ND;
    float*       orow = out + (size_t)b * S_ * ND;
    const f32x4 z4 = {0.f, 0.f, 0.f, 0.f};

    // iter s computes h_{s+1} and finishes out[s-1]; iter S_ finishes out[S_-1]
    for (int s = 0; s <= S_; ++s) {
        const int p = s & 1;

        // ---- stage 1: xe (uniform x loads), split to bf16 hi/lo -> G[p] ----
        float xv_cur = 0.0f;
        if (s < S_) {
            const float* xp = xrow + s * ND;
            xv_cur = (tid < ND) ? xp[tid] : 0.0f;
            float xe = bin_reg;
            #pragma unroll
            for (int q = 0; q < ND; ++q) xe = fmaf(xp[q], win_reg[q], xe);
            ushort xh, xl; split2(xe, xh, xl);
            ghi[p][ex] = xh; glo[p][ex] = xl;
        }

        // ---- stage 2: out[s-1] partials from h_s via uniform b128 broadcast.
        // hlds[p][oc*32..+32) was written by THIS half-wave (slot==tid) at
        // iter s-1 stage 7; LDS is in-order per wave -> race-free. Same fma
        // order as the old shuffle loop -> bit-identical.
        if (s > 0) {
            const float* hp = &hlds[p][oc * 32];
            float oacc = 0.0f;
            #pragma unroll
            for (int qq = 0; qq < 8; ++qq) {
                float4 hv = *(const float4*)(hp + qq * 4);
                oacc = fmaf(hv.x, wout[qq * 4 + 0], oacc);
                oacc = fmaf(hv.y, wout[qq * 4 + 1], oacc);
                oacc = fmaf(hv.z, wout[qq * 4 + 2], oacc);
                oacc = fmaf(hv.w, wout[qq * 4 + 3], oacc);
            }
            red[p][oc * 32 + lc] = oacc;
        }

        BAR();   // the ONE barrier: G[p] (h from s-1 tail, xe), red[p] visible

        // ---- stage 3: finish out[s-1] (global store, never drained) ----
        if (s > 0 && tid < ND) {
            float ov = xv_prev + bout_reg;
            #pragma unroll
            for (int jg = 0; jg < 16; ++jg) ov += red[p][jg * 32 + tid];
            orow[(size_t)(s - 1) * ND + tid] = ov;
        }

        if (s < S_) {
            // ---- stage 4: A-fragments (per-lane distinct 16B) + 32 MFMA ----
            bf16x8 ah0 = *(const bf16x8*)&ghi[p][ea];
            bf16x8 ah1 = *(const bf16x8*)&ghi[p][ea + 512];
            bf16x8 al0 = *(const bf16x8*)&glo[p][ea];
            bf16x8 al1 = *(const bf16x8*)&glo[p][ea + 512];

            f32x4 acc[2][2][2];      // [o'][mt][nt]
            #pragma unroll
            for (int opi = 0; opi < 2; ++opi) {
                #pragma unroll
                for (int nt = 0; nt < 2; ++nt) {
                    f32x4 t = __builtin_amdgcn_mfma_f32_16x16x32_bf16(al0, bl[opi][nt], z4, 0, 0, 0);
                    t = __builtin_amdgcn_mfma_f32_16x16x32_bf16(ah0, bl[opi][nt], t, 0, 0, 0);
                    t = __builtin_amdgcn_mfma_f32_16x16x32_bf16(al0, bh[opi][nt], t, 0, 0, 0);
                    acc[opi][0][nt] = __builtin_amdgcn_mfma_f32_16x16x32_bf16(ah0, bh[opi][nt], t, 0, 0, 0);
                    f32x4 u = __builtin_amdgcn_mfma_f32_16x16x32_bf16(al1, bl[opi][nt], z4, 0, 0, 0);
                    u = __builtin_amdgcn_mfma_f32_16x16x32_bf16(ah1, bl[opi][nt], u, 0, 0, 0);
                    u = __builtin_amdgcn_mfma_f32_16x16x32_bf16(al1, bh[opi][nt], u, 0, 0, 0);
                    acc[opi][1][nt] = __builtin_amdgcn_mfma_f32_16x16x32_bf16(ah1, bh[opi][nt], u, 0, 0, 0);
                }
            }

            // ---- stage 5: sign + XOR-fold (values identical; xor1/2 via DPP) ----
            float Y[2][2][4];
            #pragma unroll
            for (int opi = 0; opi < 2; ++opi)
                #pragma unroll
                for (int nt = 0; nt < 2; ++nt)
                    #pragma unroll
                    for (int r = 0; r < 4; ++r) {
                        float v0 = sflip(acc[opi][0][nt][r],     (smask >> (nt * 4 + r)) & 1u);
                        float v1 = sflip(acc[opi][1][nt ^ 1][r], (smask >> (8 + (nt ^ 1) * 4 + r)) & 1u);
                        Y[opi][nt][r] = v0 + v1;
                    }
            float Z[2][2];
            #pragma unroll
            for (int opi = 0; opi < 2; ++opi) {
                #pragma unroll
                for (int kt = 0; kt < 2; ++kt) {
                    float ya0 = Y[opi][kt][0] + dpp_xor1(Y[opi][kt][1]);
                    float ya2 = Y[opi][kt][2] + dpp_xor1(Y[opi][kt][3]);
                    float z = ya0 + dpp_xor2(ya2);
                    z += __shfl_xor(z, 20, 64);
                    z += __shfl_xor(z, 40, 64);
                    Z[opi][kt] = z;
                }
            }
            float d0 = __shfl(Z[0][0], cl, 64);
            float d1 = __shfl(Z[0][1], cl, 64);
            float d2 = __shfl(Z[1][0], cl, 64);
            float d3 = __shfl(Z[1][1], cl, 64);
            const float delta = (g == 0) ? d0 : (g == 1) ? d1 : (g == 2) ? d2 : d3;

            // ---- stage 6: residual + per-channel L2 normalize (same order) ----
            float hc = h_reg + delta;
            float ss = hc * hc;
            ss += dpp_xor1(ss);
            ss += dpp_xor2(ss);
            ss += __shfl_xor(ss, 4, 32);
            ss += __shfl_xor(ss, 8, 32);
            ss += __shfl_xor(ss, 16, 32);
            h_reg = hc / (sqrtf(ss) + EPS_);

            // ---- stage 7: h_{s+1} -> parity p^1 ----
            ushort hh, hl; split2(h_reg, hh, hl);
            ghi[p ^ 1][eh] = hh; glo[p ^ 1][eh] = hl;
            hlds[p ^ 1][oo * 32 + kk] = h_reg;       // slot == tid
        }

        xv_prev = xv_cur;
    }
}

extern "C" void kernel_launch(void* const* d_in, const int* in_sizes, int n_in,
                              void* d_out, int out_size, void* d_ws, size_t ws_size,
                              hipStream_t stream) {
    const float* x     = (const float*)d_in[0];
    const float* W_in  = (const float*)d_in[1];
    const float* b_in  = (const float*)d_in[2];
    const float* w_h   = (const float*)d_in[3];
    const float* w_x   = (const float*)d_in[4];
    const float* W_out = (const float*)d_in[5];
    const float* b_out = (const float*)d_in[6];
    float* outp = (float*)d_out;

    versor_kernel<<<256, 512, 0, stream>>>(x, W_in, b_in, w_h, w_x, W_out, b_out, outp);
}